// Round 9
// baseline (134.159 us; speedup 1.0000x reference)
//
#include <hip/hip_runtime.h>
#include <hip/hip_bf16.h>

// Problem constants (fixed shapes from setup_inputs)
constexpr int NPTS = 16384;   // points per batch
constexpr int NCTR = 2048;    // centers per batch
constexpr int NCH  = 64;      // feature channels
constexpr int KK   = 32;      // neighbors per center
constexpr int NB   = 2;       // batches
constexpr int NCHK = 32;      // 512-point chunks per batch
// radius^2: reference compares d2 < fp32(0.04) (python double 0.2*0.2 -> f32)
#define R2 0.04f

// -------- Kernel P: pack points -> float4 (2x,2y,2z,p2) --------
// Coords DOUBLED: d2 = (c2+p2) - ((2x)cx+(2y)cy+(2z)cz) is bit-equal to
// (c2+p2) - 2*cp (rounding commutes with *2). p2 uses the exact R1-verified
// formula (contract off) -> selection bit-identical to numpy (absmax=0).
__global__ __launch_bounds__(256) void pack_kernel(
    const float* __restrict__ points,   // (2,16384,3)
    float4* __restrict__ packed)        // ws: (2*16384) {2x,2y,2z,p2}
{
#pragma clang fp contract(off)
    const int tid = blockIdx.x * 256 + threadIdx.x;          // 0..8191
#pragma unroll
    for (int s = 0; s < 4; ++s) {
        const int i = tid + s * 8192;                        // 0..32767
        const float x = points[3 * i + 0];
        const float y = points[3 * i + 1];
        const float z = points[3 * i + 2];
        const float p2 = (x * x + y * y) + z * z;            // exact R1 formula
        packed[i] = make_float4(x + x, y + y, z + z, p2);    // doubled (exact)
    }
}

// -------- Kernel C: per-(center, chunk) hit counts. LANES = CENTERS. -----
// R2-R8 lesson: early-exit scans serialize ~32 chunk latencies on one wave
// (compiler drains vmcnt(0) per chunk). Counts need no order: each wave
// handles (64 centers x 1 chunk), reading the chunk's 512 points ONCE
// (uniform address -> broadcast) for all 64 lane-centers. 2048 uniform
// waves, issue-bound ~6us, zero tails, 16MB L2 traffic total.
__global__ __launch_bounds__(256) void count_kernel(
    const float4* __restrict__ packed,  // (2,16384) {2x,2y,2z,p2}
    const float* __restrict__ centers,  // (2,2048,3)
    unsigned short* __restrict__ cnts)  // ws: [32][4096] chunk-major
{
#pragma clang fp contract(off)
    const int wave = threadIdx.x >> 6, lane = threadIdx.x & 63;
    const int W     = blockIdx.x * 4 + wave;   // 0..2047
    const int chunk = W & 31;
    const int cgrp  = W >> 5;                  // 0..63
    const int c     = cgrp * 64 + lane;        // global center 0..4095
    const int b     = c >> 11;                 // batch uniform per wave

    const float* cc = centers + (size_t)c * 3;
    const float cx = cc[0], cy = cc[1], cz = cc[2];
    const float c2 = (cx * cx + cy * cy) + cz * cz;

    const float4* pk = packed + (size_t)b * NPTS + chunk * 512;
    int cnt0 = 0, cnt1 = 0;
    for (int j = 0; j < 512; j += 8) {
        float4 p[8];
#pragma unroll
        for (int u = 0; u < 8; ++u) p[u] = pk[j + u];        // uniform addr
#pragma unroll
        for (int u = 0; u < 8; ++u) {
            const float cp2 = (cx * p[u].x + cy * p[u].y) + cz * p[u].z;
            const float d2 = (c2 + p[u].w) - cp2;            // exact formula
            if (u & 1) cnt1 += (d2 < R2); else cnt0 += (d2 < R2);
        }
    }
    cnts[(size_t)chunk * 4096 + c] = (unsigned short)(cnt0 + cnt1);  // coalesced
}

// -------- Kernel S: select (exact slots from counts) + group ------------
// One block/center. Chunk-prefix of counts gives every hit its exact global
// slot -> the 4 waves process DISJOINT chunks (q%4==wave, only excl<KK, max
// 8 serial chunks/wave) and scatter straight into idxs[32]. No merge, no
// early-exit chain. Epilogue: direct channel-major gather from feats (no
// transpose needed), coalesced 128B stores.
__global__ __launch_bounds__(256) void select_group(
    const float4* __restrict__ packed,  // (2,16384) {2x,2y,2z,p2}
    const float* __restrict__ centers,  // (2,2048,3)
    const float* __restrict__ feats,    // (2,64,16384)
    const unsigned short* __restrict__ cnts,  // [32][4096]
    float* __restrict__ out_xyz,        // (2,3,2048,32)
    float* __restrict__ out_feat)       // (2,64,2048,32)
{
#pragma clang fp contract(off)          // keep numpy-exact d2 (absmax=0 since R1)
    __shared__ int scnt[NCHK];
    __shared__ int sexcl[NCHK];
    __shared__ int sCH, sTot;
    __shared__ int idxs[KK];

    const int t = threadIdx.x, wave = t >> 6, lane = t & 63;
    const int cg = blockIdx.x;          // 0..4095
    const int b  = cg >> 11;
    const int g  = cg & (NCTR - 1);

    const float4* pk = packed + (size_t)b * NPTS;
    const float* cc = centers + (size_t)cg * 3;
    const float cx = cc[0], cy = cc[1], cz = cc[2];
    const float c2 = (cx * cx + cy * cy) + cz * cz;

    if (t < NCHK) scnt[t] = cnts[(size_t)t * 4096 + cg];
    __syncthreads();
    if (t == 0) {
        int run = 0, CH = NCHK - 1;
        for (int q = 0; q < NCHK; ++q) {
            sexcl[q] = run;
            run += scnt[q];
            if (CH == NCHK - 1 && run >= KK) CH = q;   // chunk of the 32nd hit
        }
        sCH = CH; sTot = run;
    }
    __syncthreads();

    // ---- disjoint-chunk scan with exact global slots ----
    const int CH = sCH;
    const unsigned long long lmask = (1ull << lane) - 1ull;
    for (int q = wave; q <= CH; q += 4) {
        const int excl = sexcl[q];
        if (excl >= KK) continue;       // no slot <32 can come from this chunk
        const int base = q * 512;
        float4 v[8];
#pragma unroll
        for (int j = 0; j < 8; ++j) v[j] = pk[base + j * 64 + lane];
        unsigned long long m[8];
#pragma unroll
        for (int j = 0; j < 8; ++j) {
            const float cp2 = (cx * v[j].x + cy * v[j].y) + cz * v[j].z;
            m[j] = __ballot((c2 + v[j].w) - cp2 < R2);   // identical expr to count
        }
        int run = excl;
#pragma unroll
        for (int j = 0; j < 8; ++j) {
            if ((m[j] >> lane) & 1ull) {
                const int slot = run + __popcll(m[j] & lmask);
                if (slot < KK) idxs[slot] = base + j * 64 + lane;
            }
            run += (int)__popcll(m[j]);
        }
    }
    __syncthreads();

    // ---- pad (race-free: read first, barrier, write) + grouped_xyz ----
    const int total = sTot;
    const int cpd = total < KK ? total : KK;
    int myid = 0;
    if (t < KK) {
        const int first = (total > 0) ? idxs[0] : 0;
        myid = (t < cpd) ? idxs[t] : first;
    }
    __syncthreads();
    if (t < KK) {
        idxs[t] = myid;
        const float4 v = pk[myid];
        const float px = 0.5f * v.x, py = 0.5f * v.y, pz = 0.5f * v.z;  // exact
        const size_t ob = (((size_t)b * 3 + 0) * NCTR + g) * KK + t;
        out_xyz[ob + (size_t)0 * NCTR * KK] = (px - cx) / 0.2f;
        out_xyz[ob + (size_t)1 * NCTR * KK] = (py - cy) / 0.2f;
        out_xyz[ob + (size_t)2 * NCTR * KK] = (pz - cz) / 0.2f;
    }
    __syncthreads();

    // ---- grouped_features: direct gather, no transpose ----
    // t = (c-high, k): k = t&31; 8 channels per thread; stores are 128B
    // contiguous per 32 lanes; reads are scattered dwords (L2-resident feats).
    const int k  = t & 31;
    const int c0 = t >> 5;              // 0..7
    const int id = idxs[k];
    const float* fb = feats + (size_t)b * NCH * NPTS;
    float* ofb = out_feat + ((size_t)b * NCH * NCTR + g) * KK + k;
#pragma unroll
    for (int i = 0; i < 8; ++i) {
        const int c = c0 + 8 * i;
        ofb[(size_t)c * NCTR * KK] = fb[(size_t)c * NPTS + id];
    }
}

// -------- Fallback: R2 fused kernel (used only if ws is too small) --------
__global__ __launch_bounds__(256) void ballquery_group(
    const float* __restrict__ points, const float* __restrict__ centers,
    const float* __restrict__ feats, float* __restrict__ out_xyz,
    float* __restrict__ out_feat)
{
#pragma clang fp contract(off)
    __shared__ int   s_idx[4][KK];
    __shared__ float s_f[4][KK][65];
    const int wave = threadIdx.x >> 6, lane = threadIdx.x & 63;
    const int cg = blockIdx.x * 4 + wave;
    const int b = cg >> 11, g = cg & (NCTR - 1);
    const float* pb = points + (size_t)b * NPTS * 3;
    const float* cc = centers + (size_t)cg * 3;
    const float cx = cc[0], cy = cc[1], cz = cc[2];
    const float c2 = (cx * cx + cy * cy) + cz * cz;
    int* idxs = s_idx[wave];
    int cnt = 0;
    for (int base = 0; base < NPTS; base += 64) {
        const int i = base + lane;
        const float px = pb[i * 3 + 0], py = pb[i * 3 + 1], pz = pb[i * 3 + 2];
        const float p2 = (px * px + py * py) + pz * pz;
        const float cp = (cx * px + cy * py) + cz * pz;
        const float d2 = (c2 + p2) - 2.0f * cp;
        const bool hit = d2 < R2;
        const unsigned long long m = __ballot(hit);
        if (hit) {
            const int slot = cnt + __popcll(m & ((1ull << lane) - 1ull));
            if (slot < KK) idxs[slot] = i;
        }
        cnt += (int)__popcll(m);
        if (cnt >= KK) break;
    }
    __syncthreads();
    const int cpd = cnt < KK ? cnt : KK;
    const int first = (cnt > 0) ? idxs[0] : 0;
    if (lane < KK) idxs[lane] = (lane < cpd) ? idxs[lane] : first;
    __syncthreads();
    if (lane < KK) {
        const int id = idxs[lane];
        const float px = pb[id * 3 + 0], py = pb[id * 3 + 1], pz = pb[id * 3 + 2];
        const size_t ob = (((size_t)b * 3 + 0) * NCTR + g) * KK + lane;
        out_xyz[ob + (size_t)0 * NCTR * KK] = (px - cx) / 0.2f;
        out_xyz[ob + (size_t)1 * NCTR * KK] = (py - cy) / 0.2f;
        out_xyz[ob + (size_t)2 * NCTR * KK] = (pz - cz) / 0.2f;
    }
    float (*sf)[65] = s_f[wave];
    const float* fb = feats + (size_t)b * NCH * NPTS;
    for (int k = 0; k < KK; ++k) {
        const int id = idxs[k];
        sf[k][lane] = fb[(size_t)lane * NPTS + id];
    }
    __syncthreads();
    const int k = lane & 31, ch = lane >> 5;
    const size_t ob = ((size_t)b * NCH * NCTR + g) * KK;
#pragma unroll
    for (int cc2 = 0; cc2 < 32; ++cc2) {
        const int c = cc2 * 2 + ch;
        out_feat[ob + (size_t)c * NCTR * KK + k] = sf[k][c];
    }
}

extern "C" void kernel_launch(void* const* d_in, const int* in_sizes, int n_in,
                              void* d_out, int out_size, void* d_ws, size_t ws_size,
                              hipStream_t stream) {
    const float* points  = (const float*)d_in[0];   // (2,16384,3)
    const float* centers = (const float*)d_in[1];   // (2,2048,3)
    const float* feats   = (const float*)d_in[2];   // (2,64,16384)

    float* out      = (float*)d_out;
    float* out_xyz  = out;                                    // (2,3,2048,32)
    float* out_feat = out + (size_t)NB * 3 * NCTR * KK;       // (2,64,2048,32)

    const size_t pkBytes = (size_t)NB * NPTS * 4 * sizeof(float);        // 512 KB
    const size_t cntBytes = (size_t)NCHK * NB * NCTR * sizeof(unsigned short); // 256 KB

    if (ws_size >= pkBytes + cntBytes) {
        float4* packed = (float4*)d_ws;
        unsigned short* cnts = (unsigned short*)((char*)d_ws + pkBytes);
        pack_kernel<<<32, 256, 0, stream>>>(points, packed);
        // 2048 waves: (64 centers x 1 chunk) each
        count_kernel<<<512, 256, 0, stream>>>(packed, centers, cnts);
        // one block per center
        select_group<<<NB * NCTR, 256, 0, stream>>>(
            packed, centers, feats, cnts, out_xyz, out_feat);
    } else {
        ballquery_group<<<(NB * NCTR) / 4, 256, 0, stream>>>(
            points, centers, feats, out_xyz, out_feat);
    }
}